// Round 1
// baseline (419.191 us; speedup 1.0000x reference)
//
#include <hip/hip_runtime.h>

#define FLOWS 16
#define ROWS 2

__device__ __forceinline__ float tanh_fast(float x) {
    // tanh(x) = 1 - 2/(exp(2x)+1); saturates correctly for |x| large.
    float e = __expf(2.0f * x);
    return 1.0f - 2.0f * __builtin_amdgcn_rcpf(e + 1.0f);
}

__global__ __launch_bounds__(256) void realnvp_fwd(
    const float* __restrict__ x,
    const float* __restrict__ W1, const float* __restrict__ B1,
    const float* __restrict__ W2, const float* __restrict__ B2,
    const float* __restrict__ W3, const float* __restrict__ B3,
    const float* __restrict__ W4, const float* __restrict__ B4,
    float* __restrict__ out, int nrows)
{
    const int tid = blockIdx.x * blockDim.x + threadIdx.x;
    const int base = tid * ROWS;
    if (base + ROWS > nrows) return;  // nrows divisible by ROWS

    float z0[ROWS], z1[ROWS], ld[ROWS];
#pragma unroll
    for (int r = 0; r < ROWS; ++r) {
        float2 xv = reinterpret_cast<const float2*>(x)[base + r];
        z0[r] = xv.x; z1[r] = xv.y; ld[r] = 0.0f;
    }

#pragma unroll 1
    for (int l = 0; l < FLOWS; ++l) {
        const float* w1 = W1 + l * 10;   // (1,10)
        const float* c1 = B1 + l * 10;
        const float* w2 = W2 + l * 100;  // (10,10) [in][out]
        const float* c2 = B2 + l * 10;
        const float* w3 = W3 + l * 200;  // (10,20)
        const float* c3 = B3 + l * 20;
        const float* w4 = W4 + l * 40;   // (20,2)
        const float* c4 = B4 + l * 2;

        // h1 = relu(z0 @ W1 + b1)
        float h1[ROWS][10];
#pragma unroll
        for (int j = 0; j < 10; ++j) {
            const float wv = w1[j], bv = c1[j];
#pragma unroll
            for (int r = 0; r < ROWS; ++r)
                h1[r][j] = fmaxf(fmaf(z0[r], wv, bv), 0.0f);
        }

        // h2 = relu(h1 @ W2 + b2)
        float h2[ROWS][10];
#pragma unroll
        for (int j = 0; j < 10; ++j) {
            float acc[ROWS];
            const float bv = c2[j];
#pragma unroll
            for (int r = 0; r < ROWS; ++r) acc[r] = bv;
#pragma unroll
            for (int i = 0; i < 10; ++i) {
                const float wv = w2[i * 10 + j];
#pragma unroll
                for (int r = 0; r < ROWS; ++r) acc[r] = fmaf(h1[r][i], wv, acc[r]);
            }
#pragma unroll
            for (int r = 0; r < ROWS; ++r) h2[r][j] = fmaxf(acc[r], 0.0f);
        }

        // h3 = tanh(h2 @ W3 + b3)
        float h3[ROWS][20];
#pragma unroll
        for (int j = 0; j < 20; ++j) {
            float acc[ROWS];
            const float bv = c3[j];
#pragma unroll
            for (int r = 0; r < ROWS; ++r) acc[r] = bv;
#pragma unroll
            for (int i = 0; i < 10; ++i) {
                const float wv = w3[i * 20 + j];
#pragma unroll
                for (int r = 0; r < ROWS; ++r) acc[r] = fmaf(h2[r][i], wv, acc[r]);
            }
#pragma unroll
            for (int r = 0; r < ROWS; ++r) h3[r][j] = tanh_fast(acc[r]);
        }

        // out = h3 @ W4 + b4 -> (log_scale, shift)
        float ls[ROWS], sh[ROWS];
#pragma unroll
        for (int r = 0; r < ROWS; ++r) { ls[r] = c4[0]; sh[r] = c4[1]; }
#pragma unroll
        for (int i = 0; i < 20; ++i) {
            const float wa = w4[i * 2 + 0];
            const float wb = w4[i * 2 + 1];
#pragma unroll
            for (int r = 0; r < ROWS; ++r) {
                ls[r] = fmaf(h3[r][i], wa, ls[r]);
                sh[r] = fmaf(h3[r][i], wb, sh[r]);
            }
        }

        // coupling update + swap
#pragma unroll
        for (int r = 0; r < ROWS; ++r) {
            float t = fmaf(__expf(ls[r]), z1[r], sh[r]);
            z1[r] = z0[r];
            z0[r] = t;
            ld[r] += ls[r];
        }
    }

    // final swap: z0_new = z1f, z1_new = z0f
    float* out_lp = out;
    float2* out_z = reinterpret_cast<float2*>(out + nrows);
#pragma unroll
    for (int r = 0; r < ROWS; ++r) {
        const float z0n = z1[r], z1n = z0[r];
        // log_pz = -0.5*(z0n^2+z1n^2) - log(2*pi)
        const float lp = fmaf(-0.5f, fmaf(z0n, z0n, z1n * z1n), -1.8378770664093453f) + ld[r];
        out_lp[base + r] = lp;
        out_z[base + r] = make_float2(z0n, z1n);
    }
}

extern "C" void kernel_launch(void* const* d_in, const int* in_sizes, int n_in,
                              void* d_out, int out_size, void* d_ws, size_t ws_size,
                              hipStream_t stream) {
    const float* x  = (const float*)d_in[0];
    const float* W1 = (const float*)d_in[1];
    const float* B1 = (const float*)d_in[2];
    const float* W2 = (const float*)d_in[3];
    const float* B2 = (const float*)d_in[4];
    const float* W3 = (const float*)d_in[5];
    const float* B3 = (const float*)d_in[6];
    const float* W4 = (const float*)d_in[7];
    const float* B4 = (const float*)d_in[8];
    const int nrows = in_sizes[0] / 2;

    const int threads = 256;
    const int total_threads = (nrows + ROWS - 1) / ROWS;
    const int blocks = (total_threads + threads - 1) / threads;
    realnvp_fwd<<<blocks, threads, 0, stream>>>(x, W1, B1, W2, B2, W3, B3, W4, B4,
                                                (float*)d_out, nrows);
}

// Round 3
// 324.972 us; speedup vs baseline: 1.2899x; 1.2899x over previous
//
#include <hip/hip_runtime.h>
#include <hip/hip_fp16.h>

#define FLOWS 16
// Two batch rows packed into lo/hi halves of every __half2 register.

typedef _Float16 f16x2 __attribute__((ext_vector_type(2)));

__device__ __forceinline__ __half2 hmax2_pk(__half2 a, __half2 b) {
    f16x2 av, bv, rv;
    __builtin_memcpy(&av, &a, sizeof(av));
    __builtin_memcpy(&bv, &b, sizeof(bv));
    rv = __builtin_elementwise_max(av, bv);   // v_pk_max_f16
    __half2 r;
    __builtin_memcpy(&r, &rv, sizeof(r));
    return r;
}

// ---- weight prep: fp32 -> duplicated half2, laid out flat in d_ws ----
// dword offsets: W1=0 B1=160 W2=320 B2=1920 W3=2080 B3=5280 W4=5600 B4=6240 (total 6272)
__global__ void prep_weights(const float* __restrict__ W1, const float* __restrict__ B1,
                             const float* __restrict__ W2, const float* __restrict__ B2,
                             const float* __restrict__ W3, const float* __restrict__ B3,
                             const float* __restrict__ W4, const float* __restrict__ B4,
                             __half2* __restrict__ wsd) {
    int t = blockIdx.x * blockDim.x + threadIdx.x;
    if (t >= 6272) return;
    float v;
    if      (t <  160) v = W1[t];
    else if (t <  320) v = B1[t - 160];
    else if (t < 1920) v = W2[t - 320];
    else if (t < 2080) v = B2[t - 1920];
    else if (t < 5280) v = W3[t - 2080];
    else if (t < 5600) v = B3[t - 5280];
    else if (t < 6240) v = W4[t - 5600];
    else               v = B4[t - 6240];
    __half h = __float2half_rn(v);
    wsd[t] = __halves2half2(h, h);
}

__device__ __forceinline__ __half2 tanh2_fast(__half2 x) {
    // tanh(x) = 1 - 2/(2^(c*x)+1), c = 2*log2(e). f16 overflow saturates correctly.
    const __half2 c    = __float2half2_rn(2.8853900817779268f);
    const __half2 one  = __float2half2_rn(1.0f);
    const __half2 m2   = __float2half2_rn(-2.0f);
    __half2 e = h2exp2(__hmul2(x, c));
    __half2 r = h2rcp(__hadd2(e, one));
    return __hfma2(m2, r, one);
}

__global__ __launch_bounds__(256) void realnvp_fwd(
    const float* __restrict__ x,
    const __half2* __restrict__ wd,
    float* __restrict__ out, int nrows)
{
    const int tid  = blockIdx.x * blockDim.x + threadIdx.x;
    const int base = tid * 2;
    if (base + 2 > nrows) return;

    float2 xa = reinterpret_cast<const float2*>(x)[base + 0];
    float2 xb = reinterpret_cast<const float2*>(x)[base + 1];
    float z0a = xa.x, z1a = xa.y, lda = 0.0f;
    float z0b = xb.x, z1b = xb.y, ldb = 0.0f;

    const __half2 zero = __float2half2_rn(0.0f);

#pragma unroll 1
    for (int l = 0; l < FLOWS; ++l) {
        const __half2* w1 = wd + 0    + l * 10;
        const __half2* c1 = wd + 160  + l * 10;
        const __half2* w2 = wd + 320  + l * 100;
        const __half2* c2 = wd + 1920 + l * 10;
        const __half2* w3 = wd + 2080 + l * 200;
        const __half2* c3 = wd + 5280 + l * 20;
        const __half2* w4 = wd + 5600 + l * 40;
        const __half2* c4 = wd + 6240 + l * 2;

        // pack the two rows' z0
        __half2 z0p = __floats2half2_rn(z0a, z0b);

        // h1 = relu(z0 @ W1 + b1)  (10)
        __half2 h1[10];
#pragma unroll
        for (int j = 0; j < 10; ++j)
            h1[j] = hmax2_pk(__hfma2(z0p, w1[j], c1[j]), zero);

        // h2 = relu(h1 @ W2 + b2)  (10x10)
        __half2 h2[10];
#pragma unroll
        for (int j = 0; j < 10; ++j) {
            __half2 acc = c2[j];
#pragma unroll
            for (int i = 0; i < 10; ++i)
                acc = __hfma2(h1[i], w2[i * 10 + j], acc);
            h2[j] = hmax2_pk(acc, zero);
        }

        // h3 = tanh(h2 @ W3 + b3)  (10x20)
        __half2 h3[20];
#pragma unroll
        for (int j = 0; j < 20; ++j) {
            __half2 acc = c3[j];
#pragma unroll
            for (int i = 0; i < 10; ++i)
                acc = __hfma2(h2[i], w3[i * 20 + j], acc);
            h3[j] = tanh2_fast(acc);
        }

        // (log_scale, shift) = h3 @ W4 + b4  (20x2)
        __half2 ls = c4[0], sh = c4[1];
#pragma unroll
        for (int i = 0; i < 20; ++i) {
            ls = __hfma2(h3[i], w4[i * 2 + 0], ls);
            sh = __hfma2(h3[i], w4[i * 2 + 1], sh);
        }

        // coupling update + swap, fp32 per row
        float lsa = __half2float(__low2half(ls));
        float lsb = __half2float(__high2half(ls));
        float sha = __half2float(__low2half(sh));
        float shb = __half2float(__high2half(sh));

        float ta = fmaf(__expf(lsa), z1a, sha);
        float tb = fmaf(__expf(lsb), z1b, shb);
        z1a = z0a; z0a = ta; lda += lsa;
        z1b = z0b; z0b = tb; ldb += lsb;
    }

    // final swap: z0_new = z1f, z1_new = z0f
    float* out_lp = out;
    float2* out_z = reinterpret_cast<float2*>(out + nrows);

    const float z0na = z1a, z1na = z0a;
    const float z0nb = z1b, z1nb = z0b;
    const float lpa = fmaf(-0.5f, fmaf(z0na, z0na, z1na * z1na), -1.8378770664093453f) + lda;
    const float lpb = fmaf(-0.5f, fmaf(z0nb, z0nb, z1nb * z1nb), -1.8378770664093453f) + ldb;
    out_lp[base + 0] = lpa;
    out_lp[base + 1] = lpb;
    out_z[base + 0] = make_float2(z0na, z1na);
    out_z[base + 1] = make_float2(z0nb, z1nb);
}

extern "C" void kernel_launch(void* const* d_in, const int* in_sizes, int n_in,
                              void* d_out, int out_size, void* d_ws, size_t ws_size,
                              hipStream_t stream) {
    const float* x  = (const float*)d_in[0];
    const float* W1 = (const float*)d_in[1];
    const float* B1 = (const float*)d_in[2];
    const float* W2 = (const float*)d_in[3];
    const float* B2 = (const float*)d_in[4];
    const float* W3 = (const float*)d_in[5];
    const float* B3 = (const float*)d_in[6];
    const float* W4 = (const float*)d_in[7];
    const float* B4 = (const float*)d_in[8];
    const int nrows = in_sizes[0] / 2;

    __half2* wsd = (__half2*)d_ws;
    prep_weights<<<(6272 + 255) / 256, 256, 0, stream>>>(W1, B1, W2, B2, W3, B3, W4, B4, wsd);

    const int threads = 256;
    const int total_threads = nrows / 2;
    const int blocks = (total_threads + threads - 1) / threads;
    realnvp_fwd<<<blocks, threads, 0, stream>>>(x, wsd, (float*)d_out, nrows);
}

// Round 4
// 57.880 us; speedup vs baseline: 7.2424x; 5.6146x over previous
//
#include <hip/hip_runtime.h>
#include <hip/hip_fp16.h>

#define FLOWS 16

// ---------------- table path ----------------
// Warp: u = sign(z0) * log2(1 + |z0|/S);  S = 0.125, u in [-15, 15]
// Nodes: u_i = -15 + i * (30/2048), i = 0..2048  (30/2048 = 15/1024, exact in fp32)
// tab4[l][i] = { ls2(i), sh(i), ls2(i+1), sh(i+1) }, i = 0..2047, ls2 = log_scale*log2(e)
#define NE_TAB 2048
#define TAB_BYTES (FLOWS * NE_TAB * 16)

__device__ __forceinline__ float2 eval_mlp(int l, float z0,
        const float* __restrict__ W1, const float* __restrict__ B1,
        const float* __restrict__ W2, const float* __restrict__ B2,
        const float* __restrict__ W3, const float* __restrict__ B3,
        const float* __restrict__ W4, const float* __restrict__ B4) {
    const float* w1 = W1 + l * 10;
    const float* c1 = B1 + l * 10;
    const float* w2 = W2 + l * 100;
    const float* c2 = B2 + l * 10;
    const float* w3 = W3 + l * 200;
    const float* c3 = B3 + l * 20;
    const float* w4 = W4 + l * 40;
    const float* c4 = B4 + l * 2;

    float h1[10];
#pragma unroll
    for (int j = 0; j < 10; ++j)
        h1[j] = fmaxf(fmaf(z0, w1[j], c1[j]), 0.0f);

    float h2[10];
#pragma unroll
    for (int j = 0; j < 10; ++j) {
        float acc = c2[j];
#pragma unroll
        for (int i = 0; i < 10; ++i) acc = fmaf(h1[i], w2[i * 10 + j], acc);
        h2[j] = fmaxf(acc, 0.0f);
    }

    float h3[20];
#pragma unroll
    for (int j = 0; j < 20; ++j) {
        float acc = c3[j];
#pragma unroll
        for (int i = 0; i < 10; ++i) acc = fmaf(h2[i], w3[i * 20 + j], acc);
        h3[j] = tanhf(acc);
    }

    float ls = c4[0], sh = c4[1];
#pragma unroll
    for (int i = 0; i < 20; ++i) {
        ls = fmaf(h3[i], w4[i * 2 + 0], ls);
        sh = fmaf(h3[i], w4[i * 2 + 1], sh);
    }
    return make_float2(ls * 1.4426950408889634f, sh);  // ls2, sh
}

__device__ __forceinline__ float node_z0(int i) {
    float u = fmaf((float)i, 30.0f / 2048.0f, -15.0f);
    float m = 0.125f * (exp2f(fabsf(u)) - 1.0f);
    return u < 0.0f ? -m : m;
}

__global__ __launch_bounds__(256) void build_table(
        const float* __restrict__ W1, const float* __restrict__ B1,
        const float* __restrict__ W2, const float* __restrict__ B2,
        const float* __restrict__ W3, const float* __restrict__ B3,
        const float* __restrict__ W4, const float* __restrict__ B4,
        float4* __restrict__ tab) {
    int t = blockIdx.x * blockDim.x + threadIdx.x;
    if (t >= FLOWS * NE_TAB) return;
    int l = t / NE_TAB, i = t % NE_TAB;
    float2 r0 = eval_mlp(l, node_z0(i),     W1, B1, W2, B2, W3, B3, W4, B4);
    float2 r1 = eval_mlp(l, node_z0(i + 1), W1, B1, W2, B2, W3, B3, W4, B4);
    tab[t] = make_float4(r0.x, r0.y, r1.x, r1.y);
}

#define TROWS 4

__global__ __launch_bounds__(256) void realnvp_tab(
        const float* __restrict__ x,
        const float4* __restrict__ tab,
        float* __restrict__ out, int nrows) {
    const int tid  = blockIdx.x * blockDim.x + threadIdx.x;
    const int base = tid * TROWS;
    if (base + TROWS > nrows) return;

    float z0[TROWS], z1[TROWS], ld2[TROWS];
#pragma unroll
    for (int r = 0; r < TROWS; ++r) {
        float2 xv = reinterpret_cast<const float2*>(x)[base + r];
        z0[r] = xv.x; z1[r] = xv.y; ld2[r] = 0.0f;
    }

    const float INV_DU = 2048.0f / 30.0f;  // 1/du in u-space

#pragma unroll 1
    for (int l = 0; l < FLOWS; ++l) {
        const float4* tf = tab + l * NE_TAB;

        float fr[TROWS];
        float4 e[TROWS];
        int idx[TROWS];
#pragma unroll
        for (int r = 0; r < TROWS; ++r) {
            float a  = fmaf(fabsf(z0[r]), 8.0f, 1.0f);   // 1 + |z0|/S
            float lg = __log2f(a);
            float u  = z0[r] < 0.0f ? -lg : lg;
            float fi = fmaf(u, INV_DU, 1024.0f);
            fi = fminf(fmaxf(fi, 0.0f), 2047.999f);
            idx[r] = (int)fi;
            fr[r]  = fi - (float)idx[r];
        }
#pragma unroll
        for (int r = 0; r < TROWS; ++r)
            e[r] = tf[idx[r]];
#pragma unroll
        for (int r = 0; r < TROWS; ++r) {
            float ls2 = fmaf(fr[r], e[r].z - e[r].x, e[r].x);
            float sh  = fmaf(fr[r], e[r].w - e[r].y, e[r].y);
            float t   = fmaf(exp2f(ls2), z1[r], sh);
            z1[r] = z0[r];
            z0[r] = t;
            ld2[r] += ls2;
        }
    }

    float* out_lp = out;
    float2* out_z = reinterpret_cast<float2*>(out + nrows);
#pragma unroll
    for (int r = 0; r < TROWS; ++r) {
        const float z0n = z1[r], z1n = z0[r];
        const float ld  = ld2[r] * 0.6931471805599453f;
        const float lp  = fmaf(-0.5f, fmaf(z0n, z0n, z1n * z1n), -1.8378770664093453f) + ld;
        out_lp[base + r] = lp;
        out_z[base + r]  = make_float2(z0n, z1n);
    }
}

// ---------------- fallback: packed-f16 path (round-2, passing) ----------------
typedef _Float16 f16x2 __attribute__((ext_vector_type(2)));

__device__ __forceinline__ __half2 hmax2_pk(__half2 a, __half2 b) {
    f16x2 av, bv, rv;
    __builtin_memcpy(&av, &a, sizeof(av));
    __builtin_memcpy(&bv, &b, sizeof(bv));
    rv = __builtin_elementwise_max(av, bv);
    __half2 r;
    __builtin_memcpy(&r, &rv, sizeof(r));
    return r;
}

__global__ void prep_weights(const float* __restrict__ W1, const float* __restrict__ B1,
                             const float* __restrict__ W2, const float* __restrict__ B2,
                             const float* __restrict__ W3, const float* __restrict__ B3,
                             const float* __restrict__ W4, const float* __restrict__ B4,
                             __half2* __restrict__ wsd) {
    int t = blockIdx.x * blockDim.x + threadIdx.x;
    if (t >= 6272) return;
    float v;
    if      (t <  160) v = W1[t];
    else if (t <  320) v = B1[t - 160];
    else if (t < 1920) v = W2[t - 320];
    else if (t < 2080) v = B2[t - 1920];
    else if (t < 5280) v = W3[t - 2080];
    else if (t < 5600) v = B3[t - 5280];
    else if (t < 6240) v = W4[t - 5600];
    else               v = B4[t - 6240];
    __half h = __float2half_rn(v);
    wsd[t] = __halves2half2(h, h);
}

__device__ __forceinline__ __half2 tanh2_fast(__half2 x) {
    const __half2 c    = __float2half2_rn(2.8853900817779268f);
    const __half2 one  = __float2half2_rn(1.0f);
    const __half2 m2   = __float2half2_rn(-2.0f);
    __half2 e = h2exp2(__hmul2(x, c));
    __half2 r = h2rcp(__hadd2(e, one));
    return __hfma2(m2, r, one);
}

__global__ __launch_bounds__(256) void realnvp_fwd(
    const float* __restrict__ x,
    const __half2* __restrict__ wd,
    float* __restrict__ out, int nrows)
{
    const int tid  = blockIdx.x * blockDim.x + threadIdx.x;
    const int base = tid * 2;
    if (base + 2 > nrows) return;

    float2 xa = reinterpret_cast<const float2*>(x)[base + 0];
    float2 xb = reinterpret_cast<const float2*>(x)[base + 1];
    float z0a = xa.x, z1a = xa.y, lda = 0.0f;
    float z0b = xb.x, z1b = xb.y, ldb = 0.0f;

    const __half2 zero = __float2half2_rn(0.0f);

#pragma unroll 1
    for (int l = 0; l < FLOWS; ++l) {
        const __half2* w1 = wd + 0    + l * 10;
        const __half2* c1 = wd + 160  + l * 10;
        const __half2* w2 = wd + 320  + l * 100;
        const __half2* c2 = wd + 1920 + l * 10;
        const __half2* w3 = wd + 2080 + l * 200;
        const __half2* c3 = wd + 5280 + l * 20;
        const __half2* w4 = wd + 5600 + l * 40;
        const __half2* c4 = wd + 6240 + l * 2;

        __half2 z0p = __floats2half2_rn(z0a, z0b);

        __half2 h1[10];
#pragma unroll
        for (int j = 0; j < 10; ++j)
            h1[j] = hmax2_pk(__hfma2(z0p, w1[j], c1[j]), zero);

        __half2 h2[10];
#pragma unroll
        for (int j = 0; j < 10; ++j) {
            __half2 acc = c2[j];
#pragma unroll
            for (int i = 0; i < 10; ++i)
                acc = __hfma2(h1[i], w2[i * 10 + j], acc);
            h2[j] = hmax2_pk(acc, zero);
        }

        __half2 h3[20];
#pragma unroll
        for (int j = 0; j < 20; ++j) {
            __half2 acc = c3[j];
#pragma unroll
            for (int i = 0; i < 10; ++i)
                acc = __hfma2(h2[i], w3[i * 20 + j], acc);
            h3[j] = tanh2_fast(acc);
        }

        __half2 ls = c4[0], sh = c4[1];
#pragma unroll
        for (int i = 0; i < 20; ++i) {
            ls = __hfma2(h3[i], w4[i * 2 + 0], ls);
            sh = __hfma2(h3[i], w4[i * 2 + 1], sh);
        }

        float lsa = __half2float(__low2half(ls));
        float lsb = __half2float(__high2half(ls));
        float sha = __half2float(__low2half(sh));
        float shb = __half2float(__high2half(sh));

        float ta = fmaf(__expf(lsa), z1a, sha);
        float tb = fmaf(__expf(lsb), z1b, shb);
        z1a = z0a; z0a = ta; lda += lsa;
        z1b = z0b; z0b = tb; ldb += lsb;
    }

    float* out_lp = out;
    float2* out_z = reinterpret_cast<float2*>(out + nrows);

    const float z0na = z1a, z1na = z0a;
    const float z0nb = z1b, z1nb = z0b;
    const float lpa = fmaf(-0.5f, fmaf(z0na, z0na, z1na * z1na), -1.8378770664093453f) + lda;
    const float lpb = fmaf(-0.5f, fmaf(z0nb, z0nb, z1nb * z1nb), -1.8378770664093453f) + ldb;
    out_lp[base + 0] = lpa;
    out_lp[base + 1] = lpb;
    out_z[base + 0] = make_float2(z0na, z1na);
    out_z[base + 1] = make_float2(z0nb, z1nb);
}

// ---------------- launcher ----------------
extern "C" void kernel_launch(void* const* d_in, const int* in_sizes, int n_in,
                              void* d_out, int out_size, void* d_ws, size_t ws_size,
                              hipStream_t stream) {
    const float* x  = (const float*)d_in[0];
    const float* W1 = (const float*)d_in[1];
    const float* B1 = (const float*)d_in[2];
    const float* W2 = (const float*)d_in[3];
    const float* B2 = (const float*)d_in[4];
    const float* W3 = (const float*)d_in[5];
    const float* B3 = (const float*)d_in[6];
    const float* W4 = (const float*)d_in[7];
    const float* B4 = (const float*)d_in[8];
    const int nrows = in_sizes[0] / 2;

    if (ws_size >= (size_t)TAB_BYTES) {
        float4* tab = (float4*)d_ws;
        build_table<<<(FLOWS * NE_TAB + 255) / 256, 256, 0, stream>>>(
            W1, B1, W2, B2, W3, B3, W4, B4, tab);
        const int threads = 256;
        const int total_threads = nrows / TROWS;
        const int blocks = (total_threads + threads - 1) / threads;
        realnvp_tab<<<blocks, threads, 0, stream>>>(x, tab, (float*)d_out, nrows);
    } else {
        __half2* wsd = (__half2*)d_ws;
        prep_weights<<<(6272 + 255) / 256, 256, 0, stream>>>(W1, B1, W2, B2, W3, B3, W4, B4, wsd);
        const int threads = 256;
        const int total_threads = nrows / 2;
        const int blocks = (total_threads + threads - 1) / threads;
        realnvp_fwd<<<blocks, threads, 0, stream>>>(x, wsd, (float*)d_out, nrows);
    }
}

// Round 5
// 42.428 us; speedup vs baseline: 9.8801x; 1.3642x over previous
//
#include <hip/hip_runtime.h>
#include <hip/hip_fp16.h>

#define FLOWS 16
#define NE 2048
#define TAB_DWORDS (FLOWS * NE)      // 32768
#define TAB_BYTES  (TAB_DWORDS * 4)  // 131072

// ---------------- shared MLP evaluator (used by table builders) ----------------
__device__ __forceinline__ float2 eval_mlp(int l, float z0,
        const float* __restrict__ W1, const float* __restrict__ B1,
        const float* __restrict__ W2, const float* __restrict__ B2,
        const float* __restrict__ W3, const float* __restrict__ B3,
        const float* __restrict__ W4, const float* __restrict__ B4) {
    const float* w1 = W1 + l * 10;
    const float* c1 = B1 + l * 10;
    const float* w2 = W2 + l * 100;
    const float* c2 = B2 + l * 10;
    const float* w3 = W3 + l * 200;
    const float* c3 = B3 + l * 20;
    const float* w4 = W4 + l * 40;
    const float* c4 = B4 + l * 2;

    float h1[10];
#pragma unroll
    for (int j = 0; j < 10; ++j)
        h1[j] = fmaxf(fmaf(z0, w1[j], c1[j]), 0.0f);

    float h2[10];
#pragma unroll
    for (int j = 0; j < 10; ++j) {
        float acc = c2[j];
#pragma unroll
        for (int i = 0; i < 10; ++i) acc = fmaf(h1[i], w2[i * 10 + j], acc);
        h2[j] = fmaxf(acc, 0.0f);
    }

    float h3[20];
#pragma unroll
    for (int j = 0; j < 20; ++j) {
        float acc = c3[j];
#pragma unroll
        for (int i = 0; i < 10; ++i) acc = fmaf(h2[i], w3[i * 20 + j], acc);
        h3[j] = tanhf(acc);
    }

    float ls = c4[0], sh = c4[1];
#pragma unroll
    for (int i = 0; i < 20; ++i) {
        ls = fmaf(h3[i], w4[i * 2 + 0], ls);
        sh = fmaf(h3[i], w4[i * 2 + 1], sh);
    }
    return make_float2(ls * 1.4426950408889634f, sh);  // (log_scale*log2e, shift)
}

// Warp: u = sign(z0)*log2(1+8|z0|), u_i = -15 + i*(30/2048), i = 0..2047
__device__ __forceinline__ float node_z0(int i) {
    float u = fmaf((float)i, 30.0f / 2048.0f, -15.0f);
    float m = 0.125f * (exp2f(fabsf(u)) - 1.0f);
    return u < 0.0f ? -m : m;
}

// ---------------- f16x2 table build: dword = {ls2 f16 lo, sh f16 hi} ----------------
__global__ __launch_bounds__(256) void build_table_f16(
        const float* __restrict__ W1, const float* __restrict__ B1,
        const float* __restrict__ W2, const float* __restrict__ B2,
        const float* __restrict__ W3, const float* __restrict__ B3,
        const float* __restrict__ W4, const float* __restrict__ B4,
        unsigned int* __restrict__ gtab) {
    int t = blockIdx.x * blockDim.x + threadIdx.x;
    if (t >= TAB_DWORDS) return;
    int l = t >> 11, i = t & (NE - 1);
    float2 r = eval_mlp(l, node_z0(i), W1, B1, W2, B2, W3, B3, W4, B4);
    unsigned int lo = (unsigned int)__half_as_ushort(__float2half_rn(r.x));
    unsigned int hi = (unsigned int)__half_as_ushort(__float2half_rn(r.y));
    gtab[t] = lo | (hi << 16);
}

// ---------------- main kernel: LDS-resident table ----------------
#define TROWS 8

__global__ __launch_bounds__(1024) void realnvp_lds(
        const float* __restrict__ x,
        const unsigned int* __restrict__ gtab,
        float* __restrict__ out, int nrows) {
    __shared__ unsigned int st[TAB_DWORDS];  // 128 KB

    // stage table into LDS, 16B/lane coalesced
    {
        uint4* d = (uint4*)st;
        const uint4* s = (const uint4*)gtab;
        for (int k = threadIdx.x; k < TAB_DWORDS / 4; k += 1024) d[k] = s[k];
    }
    __syncthreads();

    const int rbase = blockIdx.x * (TROWS * 1024) + threadIdx.x;

    float z0[TROWS], z1[TROWS], ld2[TROWS];
#pragma unroll
    for (int r = 0; r < TROWS; ++r) {
        const int row = rbase + r * 1024;
        float2 xv = (row < nrows) ? reinterpret_cast<const float2*>(x)[row]
                                  : make_float2(0.0f, 0.0f);
        z0[r] = xv.x; z1[r] = xv.y; ld2[r] = 0.0f;
    }

    const float INV_DU = 2048.0f / 30.0f;

#pragma unroll 1
    for (int l = 0; l < FLOWS; ++l) {
        const unsigned int* tf = st + (l << 11);

        int   idx[TROWS];
        float fr[TROWS];
#pragma unroll
        for (int r = 0; r < TROWS; ++r) {
            float a  = fmaf(fabsf(z0[r]), 8.0f, 1.0f);   // 1 + |z0|/0.125
            float lg = __log2f(a);
            float u  = copysignf(lg, z0[r]);
            float fi = fmaf(u, INV_DU, 1024.0f);
            fi = fminf(fmaxf(fi, 0.0f), 2046.99f);       // med3 clamp
            float t = truncf(fi);
            idx[r]  = (int)t;
            fr[r]   = fi - t;
        }

        unsigned int n0[TROWS], n1[TROWS];
#pragma unroll
        for (int r = 0; r < TROWS; ++r) {
            n0[r] = tf[idx[r]];
            n1[r] = tf[idx[r] + 1];
        }

#pragma unroll
        for (int r = 0; r < TROWS; ++r) {
            float ls0 = __half2float(__ushort_as_half((unsigned short)(n0[r] & 0xffffu)));
            float sh0 = __half2float(__ushort_as_half((unsigned short)(n0[r] >> 16)));
            float ls1 = __half2float(__ushort_as_half((unsigned short)(n1[r] & 0xffffu)));
            float sh1 = __half2float(__ushort_as_half((unsigned short)(n1[r] >> 16)));
            float ls2 = fmaf(fr[r], ls1 - ls0, ls0);
            float sh  = fmaf(fr[r], sh1 - sh0, sh0);
            float t   = fmaf(exp2f(ls2), z1[r], sh);
            z1[r] = z0[r];
            z0[r] = t;
            ld2[r] += ls2;
        }
    }

    float* out_lp = out;
    float2* out_z = reinterpret_cast<float2*>(out + nrows);
#pragma unroll
    for (int r = 0; r < TROWS; ++r) {
        const int row = rbase + r * 1024;
        if (row < nrows) {
            const float z0n = z1[r], z1n = z0[r];
            const float ld  = ld2[r] * 0.6931471805599453f;
            const float lp  = fmaf(-0.5f, fmaf(z0n, z0n, z1n * z1n), -1.8378770664093453f) + ld;
            out_lp[row] = lp;
            out_z[row]  = make_float2(z0n, z1n);
        }
    }
}

// ---------------- fallback: global f32 table path (round-4, passing) ----------------
#define NE_TAB 2048
#define TAB4_BYTES (FLOWS * NE_TAB * 16)

__global__ __launch_bounds__(256) void build_table(
        const float* __restrict__ W1, const float* __restrict__ B1,
        const float* __restrict__ W2, const float* __restrict__ B2,
        const float* __restrict__ W3, const float* __restrict__ B3,
        const float* __restrict__ W4, const float* __restrict__ B4,
        float4* __restrict__ tab) {
    int t = blockIdx.x * blockDim.x + threadIdx.x;
    if (t >= FLOWS * NE_TAB) return;
    int l = t / NE_TAB, i = t % NE_TAB;
    float2 r0 = eval_mlp(l, node_z0(i),     W1, B1, W2, B2, W3, B3, W4, B4);
    float2 r1 = eval_mlp(l, node_z0(i + 1), W1, B1, W2, B2, W3, B3, W4, B4);
    tab[t] = make_float4(r0.x, r0.y, r1.x, r1.y);
}

__global__ __launch_bounds__(256) void realnvp_tab(
        const float* __restrict__ x,
        const float4* __restrict__ tab,
        float* __restrict__ out, int nrows) {
    const int tid  = blockIdx.x * blockDim.x + threadIdx.x;
    const int base = tid * 4;
    if (base + 4 > nrows) return;

    float z0[4], z1[4], ld2[4];
#pragma unroll
    for (int r = 0; r < 4; ++r) {
        float2 xv = reinterpret_cast<const float2*>(x)[base + r];
        z0[r] = xv.x; z1[r] = xv.y; ld2[r] = 0.0f;
    }
    const float INV_DU = 2048.0f / 30.0f;
#pragma unroll 1
    for (int l = 0; l < FLOWS; ++l) {
        const float4* tf = tab + l * NE_TAB;
        float fr[4]; float4 e[4]; int idx[4];
#pragma unroll
        for (int r = 0; r < 4; ++r) {
            float a  = fmaf(fabsf(z0[r]), 8.0f, 1.0f);
            float lg = __log2f(a);
            float u  = copysignf(lg, z0[r]);
            float fi = fmaf(u, INV_DU, 1024.0f);
            fi = fminf(fmaxf(fi, 0.0f), 2047.999f);
            idx[r] = (int)fi;
            fr[r]  = fi - (float)idx[r];
        }
#pragma unroll
        for (int r = 0; r < 4; ++r) e[r] = tf[idx[r]];
#pragma unroll
        for (int r = 0; r < 4; ++r) {
            float ls2 = fmaf(fr[r], e[r].z - e[r].x, e[r].x);
            float sh  = fmaf(fr[r], e[r].w - e[r].y, e[r].y);
            float t   = fmaf(exp2f(ls2), z1[r], sh);
            z1[r] = z0[r]; z0[r] = t; ld2[r] += ls2;
        }
    }
    float* out_lp = out;
    float2* out_z = reinterpret_cast<float2*>(out + nrows);
#pragma unroll
    for (int r = 0; r < 4; ++r) {
        const float z0n = z1[r], z1n = z0[r];
        const float ld  = ld2[r] * 0.6931471805599453f;
        const float lp  = fmaf(-0.5f, fmaf(z0n, z0n, z1n * z1n), -1.8378770664093453f) + ld;
        out_lp[base + r] = lp;
        out_z[base + r]  = make_float2(z0n, z1n);
    }
}

// ---------------- launcher ----------------
extern "C" void kernel_launch(void* const* d_in, const int* in_sizes, int n_in,
                              void* d_out, int out_size, void* d_ws, size_t ws_size,
                              hipStream_t stream) {
    const float* x  = (const float*)d_in[0];
    const float* W1 = (const float*)d_in[1];
    const float* B1 = (const float*)d_in[2];
    const float* W2 = (const float*)d_in[3];
    const float* B2 = (const float*)d_in[4];
    const float* W3 = (const float*)d_in[5];
    const float* B3 = (const float*)d_in[6];
    const float* W4 = (const float*)d_in[7];
    const float* B4 = (const float*)d_in[8];
    const int nrows = in_sizes[0] / 2;

    if (ws_size >= (size_t)TAB_BYTES) {
        unsigned int* gtab = (unsigned int*)d_ws;
        build_table_f16<<<(TAB_DWORDS + 255) / 256, 256, 0, stream>>>(
            W1, B1, W2, B2, W3, B3, W4, B4, gtab);
        const int rows_per_block = TROWS * 1024;
        const int blocks = (nrows + rows_per_block - 1) / rows_per_block;
        realnvp_lds<<<blocks, 1024, 0, stream>>>(x, gtab, (float*)d_out, nrows);
    } else if (ws_size >= (size_t)TAB4_BYTES) {
        float4* tab = (float4*)d_ws;
        build_table<<<(FLOWS * NE_TAB + 255) / 256, 256, 0, stream>>>(
            W1, B1, W2, B2, W3, B3, W4, B4, tab);
        const int total_threads = nrows / 4;
        const int blocks = (total_threads + 255) / 256;
        realnvp_tab<<<blocks, 256, 0, stream>>>(x, tab, (float*)d_out, nrows);
    }
}